// Round 6
// baseline (2418.647 us; speedup 1.0000x reference)
//
#include <hip/hip_runtime.h>

typedef short bf16x8 __attribute__((ext_vector_type(8)));
typedef float f32x4 __attribute__((ext_vector_type(4)));

__device__ __forceinline__ float bf2f(unsigned short u) {
    union { unsigned int i; float f; } c; c.i = ((unsigned int)u) << 16; return c.f;
}
__device__ __forceinline__ unsigned short f2bf(float f) {
    union { float f; unsigned int i; } c; c.f = f;
    unsigned int u = c.i;
    u += 0x7fffu + ((u >> 16) & 1u);          // round-to-nearest-even
    return (unsigned short)(u >> 16);
}

// async global->LDS, 16B per lane; mapping must be wave-uniform base + lane*16
__device__ __forceinline__ void gload_lds16(const unsigned short* g, unsigned short* l) {
    __builtin_amdgcn_global_load_lds(
        (const __attribute__((address_space(1))) void*)g,
        (__attribute__((address_space(3))) void*)l, 16, 0, 0);
}

// ---------------------------------------------------------------------------
// fpn fp32 NCHW [4][256][160][160] -> bf16 NHWC padded [4][162][162][256]
__global__ void transpose_pad(const float* __restrict__ x, unsigned short* __restrict__ xpad) {
    int idx = blockIdx.x * 256 + threadIdx.x;       // 3,276,800 exact
    int w = idx % 160; int t = idx / 160;
    int cv = t % 32;   t /= 32;
    int h = t % 160;   int n = t / 160;
    const float* src = x + (((size_t)(n * 256 + cv * 8) * 160 + h) * 160 + w);
    unsigned short us[8];
#pragma unroll
    for (int k = 0; k < 8; ++k) us[k] = f2bf(src[(size_t)k * 25600]);
    uint4 o;
    o.x = (unsigned int)us[0] | ((unsigned int)us[1] << 16);
    o.y = (unsigned int)us[2] | ((unsigned int)us[3] << 16);
    o.z = (unsigned int)us[4] | ((unsigned int)us[5] << 16);
    o.w = (unsigned int)us[6] | ((unsigned int)us[7] << 16);
    *(uint4*)(xpad + ((size_t)((n * 162 + h + 1) * 162) + (w + 1)) * 256 + cv * 8) = o;
}

// zero the 1-wide border of one padded NHWC buffer
__device__ __forceinline__ void zero_border_one(unsigned short* buf, int C, int idx) {
    int CV = C >> 3;
    int cv = idx % CV; int t = idx / CV;
    int p = t % 644;   int n = t / 644;
    int h, w;
    if (p < 162)      { h = 0;   w = p; }
    else if (p < 324) { h = 161; w = p - 162; }
    else { int q = p - 324; h = 1 + (q >> 1); w = (q & 1) ? 161 : 0; }
    uint4 z = make_uint4(0u, 0u, 0u, 0u);
    *(uint4*)(buf + ((size_t)((n * 162 + h) * 162) + w) * C + cv * 8) = z;
}

// all three border-zeroings in one dispatch (206080 threads exact)
__global__ void zero_all(unsigned short* __restrict__ xpad, unsigned short* __restrict__ buf1,
                         unsigned short* __restrict__ buf2) {
    int idx = blockIdx.x * 256 + threadIdx.x;
    if (idx < 82432)            zero_border_one(xpad, 256, idx);
    else if (idx < 164864)      zero_border_one(buf1, 256, idx - 82432);
    else                        zero_border_one(buf2, 128, idx - 164864);
}

// ---------------------------------------------------------------------------
// Weight pack: fp32 OIHW [CO][256][3][3] -> per-128-co-tile fragment-order:
//   tile = 294912 shorts (576KB).
//   tp in 0..3 (taps {2tp,2tp+1}): block tp*65536; within: q(0..7)*8192;
//     idx = (g*128+co)*8+e, g 0..7: tap=2tp+(g>>2), ci=q*32+(g&3)*8+e
//   tp=4 (tap 8): block 262144, q*4096; idx=(g*128+co)*8+e, g 0..3: ci=q*32+g*8+e
// Tiles 0..5: layer1 (br=t>>1, coBase=(t&1)*128) -> w1p; 6..8: layer2 -> w2p.
__global__ void pack_all(const float* __restrict__ s0, const float* __restrict__ s1,
                         const float* __restrict__ s2, const float* __restrict__ s3,
                         const float* __restrict__ s4, const float* __restrict__ s5,
                         unsigned short* __restrict__ w1p, unsigned short* __restrict__ w2p) {
    int idx = blockIdx.x * 256 + threadIdx.x;   // 9*294912 = 2,654,208 exact
    int t = idx / 294912, r = idx - t * 294912;
    const float* src; unsigned short* dst; int coBase;
    if (t < 6) {
        int br = t >> 1;
        src = (br == 0) ? s0 : (br == 1) ? s1 : s2;
        coBase = (t & 1) * 128;
        dst = w1p + (size_t)t * 294912;
    } else {
        int br = t - 6;
        src = (br == 0) ? s3 : (br == 1) ? s4 : s5;
        coBase = 0;
        dst = w2p + (size_t)br * 294912;
    }
    int tap, ci, o;
    if (r < 262144) {
        int tp = r >> 16, rem = r & 65535;
        int q = rem >> 13, r2 = rem & 8191;
        int e = r2 & 7, gco = r2 >> 3;
        int co = gco & 127, g = gco >> 7;
        tap = tp * 2 + (g >> 2);
        ci = q * 32 + (g & 3) * 8 + e;
        o = coBase + co;
    } else {
        int rem = r - 262144;
        int q = rem >> 12, r2 = rem & 4095;
        int e = r2 & 7, gco = r2 >> 3;
        int co = gco & 127, g = gco >> 7;
        tap = 8;
        ci = q * 32 + g * 8 + e;
        o = coBase + co;
    }
    dst[r] = f2bf(src[((size_t)(o * 256 + ci)) * 9 + tap]);
}

// ---------------------------------------------------------------------------
// 3x3 conv, implicit GEMM, bf16 MFMA 16x16x32.
// K-loop restructured: A (weights) loaded global->VGPR directly (L2-hot,
// per-wave vmcnt scheduling, interleaves with MFMA, no barrier). Only the
// B halo strip lives in LDS, double-buffered per ci-chunk of 32; prefetch
// for chunk q+1 issues right after the chunk-q barrier and drains one full
// chunk later. Barriers per block: 8 (was 80).
template<int COT>
__global__ __launch_bounds__(256) void conv3x3_mfma(
        const unsigned short* __restrict__ xpad,   // [4][162][162][256] bf16
        const unsigned short* __restrict__ wpk,    // packed tiles (294912 shorts each)
        unsigned short* __restrict__ ypad,         // [4][162][162][COT] bf16
        float* __restrict__ sum, float* __restrict__ sumsq) {
    __shared__ __align__(16) unsigned short Bs[2 * 2048 * 4];   // 2 bufs x 16KB

    const int tid = threadIdx.x;
    const int wv = tid >> 6, lane = tid & 63;
    const int quad = lane >> 4, l15 = lane & 15;
    const int wr = wv >> 1, wc = wv & 1;

    int bid = blockIdx.x;
    const int wt = bid % 5;
    const int ht = (bid / 5) % 40;
    const int n = (bid / 200) % 4;
    const int tile = bid / 800;            // 0..1 for COT=256, 0 for COT=128
    const int co0 = tile * 128;
    const int h0 = ht * 4, w0 = wt * 32;   // halo origin in padded coords

    const unsigned short* wtile = wpk + (size_t)tile * 294912;
    // strip source: per-thread position (clamped), fixed across q
    int p = tid; if (p > 203) p = 203;
    const int ph = p / 34, pw = p - ph * 34;
    const unsigned short* bsrc0 = xpad +
        ((size_t)((n * 162 + h0 + ph) * 162) + (w0 + pw)) * 256;

    // b-frag base positions for this wave's 4 spatial frags
    int p0[4];
#pragma unroll
    for (int j = 0; j < 4; ++j) {
        int sp = wc * 64 + j * 16 + l15;
        p0[j] = (sp >> 5) * 34 + (sp & 31);
    }
    // per-lane A fragment offset within a (tp,q) block
    const int aoff = (wr * 64 + l15) * 8;

    f32x4 acc[4][4];
#pragma unroll
    for (int i = 0; i < 4; ++i)
#pragma unroll
        for (int j = 0; j < 4; ++j) acc[i][j] = (f32x4){0.f, 0.f, 0.f, 0.f};

    // stage chunk 0 into buffer 0
#pragma unroll
    for (int g = 0; g < 4; ++g)
        gload_lds16(bsrc0 + g * 8, (unsigned short*)Bs + g * 2048 + tid * 8);
    __syncthreads();

    for (int q = 0; q < 8; ++q) {          // ci chunk of 32
        const int cur = q & 1;
        if (q < 7) {                       // prefetch next strip into other buffer
            const unsigned short* bsrc = bsrc0 + (q + 1) * 32;
            unsigned short* dst = (unsigned short*)Bs + (cur ^ 1) * 8192 + tid * 8;
#pragma unroll
            for (int g = 0; g < 4; ++g)
                gload_lds16(bsrc + g * 8, dst + g * 2048);
        }
        const unsigned short* Bb = Bs + cur * 8192;
#pragma unroll
        for (int tp = 0; tp < 5; ++tp) {   // tap pairs {0,1}{2,3}{4,5}{6,7}{8}
#pragma unroll
            for (int ts = 0; ts < 2; ++ts) {
                if (tp == 4 && ts == 1) continue;   // folds at compile time
                const int tap = tp * 2 + ts;
                const int dh = tap / 3, dw = tap % 3;
                const int toff = dh * 34 + dw;
                const int g0 = (tp < 4 ? ts * 4 : 0) + quad;
                // A fragments straight from global (L2-hot packed layout)
                const unsigned short* ap = (tp < 4)
                    ? (wtile + tp * 65536 + q * 8192 + g0 * 1024 + aoff)
                    : (wtile + 262144 + q * 4096 + g0 * 1024 + aoff);
                bf16x8 a[4], b[4];
#pragma unroll
                for (int i = 0; i < 4; ++i)
                    a[i] = *(const bf16x8*)(ap + i * 128);
#pragma unroll
                for (int j = 0; j < 4; ++j)
                    b[j] = *(const bf16x8*)(Bb + ((size_t)(quad * 256 + p0[j] + toff)) * 8);
#pragma unroll
                for (int i = 0; i < 4; ++i)
#pragma unroll
                    for (int j = 0; j < 4; ++j)
                        acc[i][j] = __builtin_amdgcn_mfma_f32_16x16x32_bf16(a[i], b[j], acc[i][j], 0, 0, 0);
            }
        }
        __syncthreads();   // reads of cur done (next iter overwrites it) + prefetch drained
    }

    // epilogue: store y (bf16, NHWC padded interior) + BN partial stats
#pragma unroll
    for (int i = 0; i < 4; ++i) {
        const int co_l = wr * 64 + i * 16 + quad * 4;
#pragma unroll
        for (int j = 0; j < 4; ++j) {
            const int sp = wc * 64 + j * 16 + l15;
            const int jh = sp >> 5, jw = sp & 31;
            f32x4 v = acc[i][j];
            ushort4 pk;
            pk.x = f2bf(v[0]); pk.y = f2bf(v[1]); pk.z = f2bf(v[2]); pk.w = f2bf(v[3]);
            *(ushort4*)(ypad + ((size_t)((n * 162 + h0 + jh + 1) * 162) + (w0 + jw + 1)) * COT
                        + co0 + co_l) = pk;
        }
#pragma unroll
        for (int r = 0; r < 4; ++r) {
            float s1 = 0.f, s2 = 0.f;
#pragma unroll
            for (int j = 0; j < 4; ++j) { float v = acc[i][j][r]; s1 += v; s2 += v * v; }
#pragma unroll
            for (int m = 1; m < 16; m <<= 1) {
                s1 += __shfl_xor(s1, m, 64);
                s2 += __shfl_xor(s2, m, 64);
            }
            if (l15 == 0) {
                atomicAdd(&sum[co0 + co_l + r], s1);
                atomicAdd(&sumsq[co0 + co_l + r], s2);
            }
        }
    }
}

// ---------------------------------------------------------------------------
// fused BN finalize + in-place relu(y*scale+shift) over padded NHWC interior
template<int C>
__global__ void bn_apply(unsigned short* __restrict__ buf,
                         const float* __restrict__ sum, const float* __restrict__ sumsq,
                         const float* __restrict__ gamma, const float* __restrict__ beta) {
    __shared__ float s_sc[C], s_sh[C];
    if (threadIdx.x < C) {
        int c = threadIdx.x;
        const float inv = 1.0f / 102400.0f;
        float m = sum[c] * inv;
        float v = sumsq[c] * inv - m * m;
        float sc = gamma[c] * rsqrtf(v + 1e-5f);
        s_sc[c] = sc;
        s_sh[c] = beta[c] - m * sc;
    }
    __syncthreads();

    constexpr int CV = C / 8;
    int idx = blockIdx.x * 256 + threadIdx.x;       // 4*25600*CV exact
    int cv = idx % CV; int pos = idx / CV;
    int w = pos % 160; int h = (pos / 160) % 160; int n = pos / 25600;
    unsigned short* p = buf + ((size_t)((n * 162 + h + 1) * 162) + (w + 1)) * C + cv * 8;
    uint4 v = *(const uint4*)p;
    unsigned int ua[4] = {v.x, v.y, v.z, v.w};
    unsigned int ob[4];
#pragma unroll
    for (int j = 0; j < 4; ++j) {
        int c = cv * 8 + j * 2;
        float f0 = bf2f((unsigned short)(ua[j] & 0xffffu)) * s_sc[c] + s_sh[c];
        float f1 = bf2f((unsigned short)(ua[j] >> 16)) * s_sc[c + 1] + s_sh[c + 1];
        f0 = fmaxf(f0, 0.f); f1 = fmaxf(f1, 0.f);
        ob[j] = (unsigned int)f2bf(f0) | ((unsigned int)f2bf(f1) << 16);
    }
    uint4 o = make_uint4(ob[0], ob[1], ob[2], ob[3]);
    *(uint4*)p = o;
}

// ---------------------------------------------------------------------------
// head conv: z [4][162][162][128] bf16 padded -> out [4][CO][160][160] fp32 (+bias)
template<int CO>
__global__ __launch_bounds__(256) void head_conv(const unsigned short* __restrict__ z,
                                                 const float* __restrict__ w,
                                                 const float* __restrict__ bias,
                                                 float* __restrict__ out) {
    __shared__ float s_w[CO * 9 * 128];
    for (int t = threadIdx.x; t < CO * 9 * 128; t += 256) {
        int ci = t % 128; int r = t / 128;
        int tap = r % 9;  int o = r / 9;
        s_w[t] = w[((size_t)(o * 128 + ci)) * 9 + tap];
    }
    __syncthreads();

    const int pos = blockIdx.x * 256 + threadIdx.x;   // 102400 exact
    const int pw = pos % 160, ph = (pos / 160) % 160, pn = pos / 25600;
    float acc[CO];
#pragma unroll
    for (int o = 0; o < CO; ++o) acc[o] = bias[o];

#pragma unroll
    for (int dh = 0; dh < 3; ++dh)
#pragma unroll
        for (int dw = 0; dw < 3; ++dw) {
            const int tap = dh * 3 + dw;
            const unsigned short* zp = z + ((size_t)((pn * 162 + ph + dh) * 162) + (pw + dw)) * 128;
            for (int c8 = 0; c8 < 16; ++c8) {
                uint4 v = *(const uint4*)(zp + c8 * 8);
                unsigned int ua[4] = {v.x, v.y, v.z, v.w};
                float xv[8];
#pragma unroll
                for (int j = 0; j < 4; ++j) {
                    xv[2 * j]     = bf2f((unsigned short)(ua[j] & 0xffffu));
                    xv[2 * j + 1] = bf2f((unsigned short)(ua[j] >> 16));
                }
#pragma unroll
                for (int o = 0; o < CO; ++o) {
                    const float* wp = &s_w[(o * 9 + tap) * 128 + c8 * 8];
                    float4 w0 = *(const float4*)wp;
                    float4 w1 = *(const float4*)(wp + 4);
                    acc[o] = fmaf(xv[0], w0.x, acc[o]);
                    acc[o] = fmaf(xv[1], w0.y, acc[o]);
                    acc[o] = fmaf(xv[2], w0.z, acc[o]);
                    acc[o] = fmaf(xv[3], w0.w, acc[o]);
                    acc[o] = fmaf(xv[4], w1.x, acc[o]);
                    acc[o] = fmaf(xv[5], w1.y, acc[o]);
                    acc[o] = fmaf(xv[6], w1.z, acc[o]);
                    acc[o] = fmaf(xv[7], w1.w, acc[o]);
                }
            }
        }
#pragma unroll
    for (int o = 0; o < CO; ++o)
        out[((size_t)(pn * CO + o)) * 25600 + ph * 160 + pw] = acc[o];
}

// two CO=1 heads fused (shrink + centroid, both read buf2 of branch 0)
__global__ __launch_bounds__(256) void head_conv_dual(const unsigned short* __restrict__ z,
                                                      const float* __restrict__ w1, const float* __restrict__ b1,
                                                      const float* __restrict__ w2, const float* __restrict__ b2,
                                                      float* __restrict__ out1, float* __restrict__ out2) {
    __shared__ float s_w[2 * 9 * 128];
    for (int t = threadIdx.x; t < 2 * 9 * 128; t += 256) {
        int ci = t % 128; int r = t / 128;
        int tap = r % 9;  int which = r / 9;
        const float* src = which ? w2 : w1;
        s_w[t] = src[(size_t)ci * 9 + tap];
    }
    __syncthreads();

    const int pos = blockIdx.x * 256 + threadIdx.x;
    const int pw = pos % 160, ph = (pos / 160) % 160, pn = pos / 25600;
    float a1 = b1[0], a2 = b2[0];

#pragma unroll
    for (int dh = 0; dh < 3; ++dh)
#pragma unroll
        for (int dw = 0; dw < 3; ++dw) {
            const int tap = dh * 3 + dw;
            const unsigned short* zp = z + ((size_t)((pn * 162 + ph + dh) * 162) + (pw + dw)) * 128;
            for (int c8 = 0; c8 < 16; ++c8) {
                uint4 v = *(const uint4*)(zp + c8 * 8);
                unsigned int ua[4] = {v.x, v.y, v.z, v.w};
                float xv[8];
#pragma unroll
                for (int j = 0; j < 4; ++j) {
                    xv[2 * j]     = bf2f((unsigned short)(ua[j] & 0xffffu));
                    xv[2 * j + 1] = bf2f((unsigned short)(ua[j] >> 16));
                }
                const float* wp1 = &s_w[tap * 128 + c8 * 8];
                const float* wp2 = &s_w[1152 + tap * 128 + c8 * 8];
#pragma unroll
                for (int e = 0; e < 8; ++e) {
                    a1 = fmaf(xv[e], wp1[e], a1);
                    a2 = fmaf(xv[e], wp2[e], a2);
                }
            }
        }
    out1[(size_t)pn * 25600 + ph * 160 + pw] = a1;
    out2[(size_t)pn * 25600 + ph * 160 + pw] = a2;
}

// ---------------------------------------------------------------------------
extern "C" void kernel_launch(void* const* d_in, const int* in_sizes, int n_in,
                              void* d_out, int out_size, void* d_ws, size_t ws_size,
                              hipStream_t stream) {
    const float* fpn = (const float*)d_in[0];
    const float* W1[3] = {(const float*)d_in[1],  (const float*)d_in[11], (const float*)d_in[19]};
    const float* G1[3] = {(const float*)d_in[2],  (const float*)d_in[12], (const float*)d_in[20]};
    const float* B1[3] = {(const float*)d_in[3],  (const float*)d_in[13], (const float*)d_in[21]};
    const float* W2[3] = {(const float*)d_in[4],  (const float*)d_in[14], (const float*)d_in[22]};
    const float* G2[3] = {(const float*)d_in[5],  (const float*)d_in[15], (const float*)d_in[23]};
    const float* B2[3] = {(const float*)d_in[6],  (const float*)d_in[16], (const float*)d_in[24]};
    const float* w_shrink = (const float*)d_in[7];  const float* b_shrink = (const float*)d_in[8];
    const float* w_cent   = (const float*)d_in[9];  const float* b_cent   = (const float*)d_in[10];
    const float* w_p3     = (const float*)d_in[17]; const float* b_p3     = (const float*)d_in[18];
    const float* w_s3     = (const float*)d_in[25]; const float* b_s3     = (const float*)d_in[26];
    float* out = (float*)d_out;

    char* ws = (char*)d_ws;
    size_t off = 0;
    unsigned short* xpad = (unsigned short*)(ws + off); off += (size_t)4 * 162 * 162 * 256 * 2;
    unsigned short* buf1 = (unsigned short*)(ws + off); off += (size_t)4 * 162 * 162 * 256 * 2;
    unsigned short* buf2 = (unsigned short*)(ws + off); off += (size_t)4 * 162 * 162 * 128 * 2;
    unsigned short* w1p  = (unsigned short*)(ws + off); off += (size_t)6 * 294912 * 2;
    unsigned short* w2p  = (unsigned short*)(ws + off); off += (size_t)3 * 294912 * 2;
    float* stats         = (float*)(ws + off);          off += (size_t)6 * 512 * 4;

    hipMemsetAsync(stats, 0, 6 * 512 * 4, stream);
    zero_all<<<805, 256, 0, stream>>>(xpad, buf1, buf2);
    transpose_pad<<<12800, 256, 0, stream>>>(fpn, xpad);
    pack_all<<<10368, 256, 0, stream>>>(W1[0], W1[1], W1[2], W2[0], W2[1], W2[2], w1p, w2p);

    for (int br = 0; br < 3; ++br) {
        float* sum1 = stats + (size_t)(br * 2 + 0) * 512; float* sq1 = sum1 + 256;
        float* sum2 = stats + (size_t)(br * 2 + 1) * 512; float* sq2 = sum2 + 256;

        conv3x3_mfma<256><<<1600, 256, 0, stream>>>(xpad, w1p + (size_t)br * 2 * 294912,
                                                    buf1, sum1, sq1);
        bn_apply<256><<<12800, 256, 0, stream>>>(buf1, sum1, sq1, G1[br], B1[br]);

        conv3x3_mfma<128><<<800, 256, 0, stream>>>(buf1, w2p + (size_t)br * 294912,
                                                   buf2, sum2, sq2);
        bn_apply<128><<<6400, 256, 0, stream>>>(buf2, sum2, sq2, G2[br], B2[br]);

        if (br == 0) {
            head_conv_dual<<<400, 256, 0, stream>>>(buf2, w_shrink, b_shrink, w_cent, b_cent,
                                                    out, out + 102400);
        } else if (br == 1) {
            head_conv<2><<<400, 256, 0, stream>>>(buf2, w_p3, b_p3, out + 204800);
        } else {
            head_conv<8><<<400, 256, 0, stream>>>(buf2, w_s3, b_s3, out + 409600);
        }
    }
}

// Round 7
// 1779.133 us; speedup vs baseline: 1.3595x; 1.3595x over previous
//
#include <hip/hip_runtime.h>

typedef short bf16x8 __attribute__((ext_vector_type(8)));
typedef float f32x4 __attribute__((ext_vector_type(4)));

__device__ __forceinline__ float bf2f(unsigned short u) {
    union { unsigned int i; float f; } c; c.i = ((unsigned int)u) << 16; return c.f;
}
__device__ __forceinline__ unsigned short f2bf(float f) {
    union { float f; unsigned int i; } c; c.f = f;
    unsigned int u = c.i;
    u += 0x7fffu + ((u >> 16) & 1u);          // round-to-nearest-even
    return (unsigned short)(u >> 16);
}

// async global->LDS, 16B per lane; mapping must be wave-uniform base + lane*16
__device__ __forceinline__ void gload_lds16(const unsigned short* g, unsigned short* l) {
    __builtin_amdgcn_global_load_lds(
        (const __attribute__((address_space(1))) void*)g,
        (__attribute__((address_space(3))) void*)l, 16, 0, 0);
}

// ---------------------------------------------------------------------------
// fpn fp32 NCHW [4][256][160][160] -> bf16 NHWC padded [4][162][162][256]
__global__ void transpose_pad(const float* __restrict__ x, unsigned short* __restrict__ xpad) {
    int idx = blockIdx.x * 256 + threadIdx.x;       // 3,276,800 exact
    int w = idx % 160; int t = idx / 160;
    int cv = t % 32;   t /= 32;
    int h = t % 160;   int n = t / 160;
    const float* src = x + (((size_t)(n * 256 + cv * 8) * 160 + h) * 160 + w);
    unsigned short us[8];
#pragma unroll
    for (int k = 0; k < 8; ++k) us[k] = f2bf(src[(size_t)k * 25600]);
    uint4 o;
    o.x = (unsigned int)us[0] | ((unsigned int)us[1] << 16);
    o.y = (unsigned int)us[2] | ((unsigned int)us[3] << 16);
    o.z = (unsigned int)us[4] | ((unsigned int)us[5] << 16);
    o.w = (unsigned int)us[6] | ((unsigned int)us[7] << 16);
    *(uint4*)(xpad + ((size_t)((n * 162 + h + 1) * 162) + (w + 1)) * 256 + cv * 8) = o;
}

// zero the 1-wide border of one padded NHWC buffer
__device__ __forceinline__ void zero_border_one(unsigned short* buf, int C, int idx) {
    int CV = C >> 3;
    int cv = idx % CV; int t = idx / CV;
    int p = t % 644;   int n = t / 644;
    int h, w;
    if (p < 162)      { h = 0;   w = p; }
    else if (p < 324) { h = 161; w = p - 162; }
    else { int q = p - 324; h = 1 + (q >> 1); w = (q & 1) ? 161 : 0; }
    uint4 z = make_uint4(0u, 0u, 0u, 0u);
    *(uint4*)(buf + ((size_t)((n * 162 + h) * 162) + w) * C + cv * 8) = z;
}

// border-zero xpad + nbr buf1's (C=256) + nbr buf2's (C=128), one dispatch
__global__ void zero_all(unsigned short* __restrict__ xpad,
                         unsigned short* __restrict__ buf1, size_t s1,
                         unsigned short* __restrict__ buf2, size_t s2, int nbr) {
    int idx = blockIdx.x * 256 + threadIdx.x;
    if (idx < 82432) { zero_border_one(xpad, 256, idx); return; }
    idx -= 82432;
    int nb1 = nbr * 82432;
    if (idx < nb1) { zero_border_one(buf1 + (size_t)(idx / 82432) * s1, 256, idx % 82432); return; }
    idx -= nb1;
    int nb2 = nbr * 41216;
    if (idx < nb2) { zero_border_one(buf2 + (size_t)(idx / 41216) * s2, 128, idx % 41216); }
}

// ---------------------------------------------------------------------------
// Weight pack: fp32 OIHW [CO][256][3][3] -> per-128-co-tile fragment-order:
//   tile = 294912 shorts (576KB).
//   tp in 0..3 (taps {2tp,2tp+1}): block tp*65536; within: q(0..7)*8192;
//     idx = (g*128+co)*8+e, g 0..7: tap=2tp+(g>>2), ci=q*32+(g&3)*8+e
//   tp=4 (tap 8): block 262144, q*4096; idx=(g*128+co)*8+e, g 0..3: ci=q*32+g*8+e
// Tiles 0..5: layer1 (br=t>>1, coBase=(t&1)*128) -> w1p; 6..8: layer2 -> w2p.
__global__ void pack_all(const float* __restrict__ s0, const float* __restrict__ s1,
                         const float* __restrict__ s2, const float* __restrict__ s3,
                         const float* __restrict__ s4, const float* __restrict__ s5,
                         unsigned short* __restrict__ w1p, unsigned short* __restrict__ w2p) {
    int idx = blockIdx.x * 256 + threadIdx.x;   // 9*294912 = 2,654,208 exact
    int t = idx / 294912, r = idx - t * 294912;
    const float* src; unsigned short* dst; int coBase;
    if (t < 6) {
        int br = t >> 1;
        src = (br == 0) ? s0 : (br == 1) ? s1 : s2;
        coBase = (t & 1) * 128;
        dst = w1p + (size_t)t * 294912;
    } else {
        int br = t - 6;
        src = (br == 0) ? s3 : (br == 1) ? s4 : s5;
        coBase = 0;
        dst = w2p + (size_t)br * 294912;
    }
    int tap, ci, o;
    if (r < 262144) {
        int tp = r >> 16, rem = r & 65535;
        int q = rem >> 13, r2 = rem & 8191;
        int e = r2 & 7, gco = r2 >> 3;
        int co = gco & 127, g = gco >> 7;
        tap = tp * 2 + (g >> 2);
        ci = q * 32 + (g & 3) * 8 + e;
        o = coBase + co;
    } else {
        int rem = r - 262144;
        int q = rem >> 12, r2 = rem & 4095;
        int e = r2 & 7, gco = r2 >> 3;
        int co = gco & 127, g = gco >> 7;
        tap = 8;
        ci = q * 32 + g * 8 + e;
        o = coBase + co;
    }
    dst[r] = f2bf(src[((size_t)(o * 256 + ci)) * 9 + tap]);
}

// ---------------------------------------------------------------------------
// 3x3 conv, implicit GEMM, bf16 MFMA 16x16x32, strip-resident B at 32KB LDS
// (R5's proven structure). BPB = blocks per branch (compile-time divisor);
// branch-fused dispatch selects per-branch x/w/y/stats via strides.
template<int COT, int BPB>
__global__ __launch_bounds__(256) void conv3x3_mfma(
        const unsigned short* __restrict__ xpad0, size_t xstride,
        const unsigned short* __restrict__ wpk0, size_t wstride,
        unsigned short* __restrict__ ypad0, size_t ystride,
        float* __restrict__ stats, int sstride) {
    __shared__ __align__(16) unsigned short Bs[4 * 256 * 8];   // [kg4][p256][8] 16KB
    __shared__ __align__(16) unsigned short As[8 * 128 * 8];   // [g8][co128][8] 16KB

    const int br = blockIdx.x / BPB;
    int bid = blockIdx.x % BPB;
    const unsigned short* xpad = xpad0 + (size_t)br * xstride;
    const unsigned short* wpk  = wpk0 + (size_t)br * wstride;
    unsigned short* ypad       = ypad0 + (size_t)br * ystride;
    float* sum   = stats + (size_t)br * sstride;
    float* sumsq = sum + 256;

    const int tid = threadIdx.x;
    const int wv = tid >> 6, lane = tid & 63;
    const int quad = lane >> 4, l15 = lane & 15;
    const int wr = wv >> 1, wc = wv & 1;

    const int wt = bid % 5;
    const int ht = (bid / 5) % 40;
    const int n = (bid / 200) % 4;
    const int tile = bid / 800;            // 0..1 for COT=256, 0 for COT=128
    const int co0 = tile * 128;
    const int h0 = ht * 4, w0 = wt * 32;   // halo origin in padded coords

    const unsigned short* wtile = wpk + (size_t)tile * 294912;
    // strip source: per-thread position (clamped), fixed across q
    int p = tid; if (p > 203) p = 203;
    const int ph = p / 34, pw = p - ph * 34;
    const unsigned short* bsrc0 = xpad +
        ((size_t)((n * 162 + h0 + ph) * 162) + (w0 + pw)) * 256;

    // b-frag base positions for this wave's 4 spatial frags
    int p0[4];
#pragma unroll
    for (int j = 0; j < 4; ++j) {
        int sp = wc * 64 + j * 16 + l15;
        p0[j] = (sp >> 5) * 34 + (sp & 31);
    }

    f32x4 acc[4][4];
#pragma unroll
    for (int i = 0; i < 4; ++i)
#pragma unroll
        for (int j = 0; j < 4; ++j) acc[i][j] = (f32x4){0.f, 0.f, 0.f, 0.f};

    for (int q = 0; q < 8; ++q) {          // ci chunk of 32
#pragma unroll
        for (int tp = 0; tp < 5; ++tp) {   // tap pairs {0,1}{2,3}{4,5}{6,7}{8}
            __syncthreads();               // prior window's LDS reads complete
            if (tp < 4) {
                const unsigned short* asrc = wtile + tp * 65536 + q * 8192 + tid * 8;
#pragma unroll
                for (int c = 0; c < 4; ++c)
                    gload_lds16(asrc + c * 2048, (unsigned short*)As + c * 2048 + tid * 8);
            } else {
                const unsigned short* asrc = wtile + 262144 + q * 4096 + tid * 8;
#pragma unroll
                for (int c = 0; c < 2; ++c)
                    gload_lds16(asrc + c * 2048, (unsigned short*)As + c * 2048 + tid * 8);
            }
            if (tp == 0) {
                const unsigned short* bsrc = bsrc0 + q * 32;
#pragma unroll
                for (int g = 0; g < 4; ++g)
                    gload_lds16(bsrc + g * 8, (unsigned short*)Bs + g * 2048 + tid * 8);
            }
            __syncthreads();               // drain DMA: tiles ready
#pragma unroll
            for (int ts = 0; ts < 2; ++ts) {
                if (tp == 4 && ts == 1) continue;   // folds at compile time
                const int tap = tp * 2 + ts;
                const int dh = tap / 3, dw = tap % 3;
                const int toff = dh * 34 + dw;
                const int g0 = (tp < 4 ? ts * 4 : 0) + quad;
                bf16x8 a[4], b[4];
#pragma unroll
                for (int i = 0; i < 4; ++i)
                    a[i] = *(const bf16x8*)(As + ((size_t)(g0 * 128 + wr * 64 + i * 16 + l15)) * 8);
#pragma unroll
                for (int j = 0; j < 4; ++j)
                    b[j] = *(const bf16x8*)(Bs + ((size_t)(quad * 256 + p0[j] + toff)) * 8);
#pragma unroll
                for (int i = 0; i < 4; ++i)
#pragma unroll
                    for (int j = 0; j < 4; ++j)
                        acc[i][j] = __builtin_amdgcn_mfma_f32_16x16x32_bf16(a[i], b[j], acc[i][j], 0, 0, 0);
            }
        }
    }

    // epilogue: store y (bf16, NHWC padded interior) + BN partial stats
#pragma unroll
    for (int i = 0; i < 4; ++i) {
        const int co_l = wr * 64 + i * 16 + quad * 4;
#pragma unroll
        for (int j = 0; j < 4; ++j) {
            const int sp = wc * 64 + j * 16 + l15;
            const int jh = sp >> 5, jw = sp & 31;
            f32x4 v = acc[i][j];
            ushort4 pk;
            pk.x = f2bf(v[0]); pk.y = f2bf(v[1]); pk.z = f2bf(v[2]); pk.w = f2bf(v[3]);
            *(ushort4*)(ypad + ((size_t)((n * 162 + h0 + jh + 1) * 162) + (w0 + jw + 1)) * COT
                        + co0 + co_l) = pk;
        }
#pragma unroll
        for (int r = 0; r < 4; ++r) {
            float s1 = 0.f, s2 = 0.f;
#pragma unroll
            for (int j = 0; j < 4; ++j) { float v = acc[i][j][r]; s1 += v; s2 += v * v; }
#pragma unroll
            for (int m = 1; m < 16; m <<= 1) {
                s1 += __shfl_xor(s1, m, 64);
                s2 += __shfl_xor(s2, m, 64);
            }
            if (l15 == 0) {
                atomicAdd(&sum[co0 + co_l + r], s1);
                atomicAdd(&sumsq[co0 + co_l + r], s2);
            }
        }
    }
}

// ---------------------------------------------------------------------------
// fused BN finalize + in-place relu(y*scale+shift); branch-fused via BPB
template<int C, int BPB>
__global__ void bn_apply(unsigned short* __restrict__ buf0, size_t bstride,
                         const float* __restrict__ stats, int sstride,
                         const float* g0, const float* g1, const float* g2,
                         const float* be0, const float* be1, const float* be2) {
    const int br = blockIdx.x / BPB;
    unsigned short* buf = buf0 + (size_t)br * bstride;
    const float* sum = stats + (size_t)br * sstride;
    const float* sumsq = sum + 256;
    const float* gamma = (br == 0) ? g0 : (br == 1) ? g1 : g2;
    const float* beta  = (br == 0) ? be0 : (br == 1) ? be1 : be2;

    __shared__ float s_sc[C], s_sh[C];
    if (threadIdx.x < C) {
        int c = threadIdx.x;
        const float inv = 1.0f / 102400.0f;
        float m = sum[c] * inv;
        float v = sumsq[c] * inv - m * m;
        float sc = gamma[c] * rsqrtf(v + 1e-5f);
        s_sc[c] = sc;
        s_sh[c] = beta[c] - m * sc;
    }
    __syncthreads();

    constexpr int CV = C / 8;
    int idx = (blockIdx.x % BPB) * 256 + threadIdx.x;   // 4*25600*CV exact per branch
    int cv = idx % CV; int pos = idx / CV;
    int w = pos % 160; int h = (pos / 160) % 160; int n = pos / 25600;
    unsigned short* p = buf + ((size_t)((n * 162 + h + 1) * 162) + (w + 1)) * C + cv * 8;
    uint4 v = *(const uint4*)p;
    unsigned int ua[4] = {v.x, v.y, v.z, v.w};
    unsigned int ob[4];
#pragma unroll
    for (int j = 0; j < 4; ++j) {
        int c = cv * 8 + j * 2;
        float f0 = bf2f((unsigned short)(ua[j] & 0xffffu)) * s_sc[c] + s_sh[c];
        float f1 = bf2f((unsigned short)(ua[j] >> 16)) * s_sc[c + 1] + s_sh[c + 1];
        f0 = fmaxf(f0, 0.f); f1 = fmaxf(f1, 0.f);
        ob[j] = (unsigned int)f2bf(f0) | ((unsigned int)f2bf(f1) << 16);
    }
    uint4 o = make_uint4(ob[0], ob[1], ob[2], ob[3]);
    *(uint4*)p = o;
}

// ---------------------------------------------------------------------------
// head conv: z [4][162][162][128] bf16 padded -> out [4][CO][160][160] fp32 (+bias)
template<int CO>
__global__ __launch_bounds__(256) void head_conv(const unsigned short* __restrict__ z,
                                                 const float* __restrict__ w,
                                                 const float* __restrict__ bias,
                                                 float* __restrict__ out) {
    __shared__ float s_w[CO * 9 * 128];
    for (int t = threadIdx.x; t < CO * 9 * 128; t += 256) {
        int ci = t % 128; int r = t / 128;
        int tap = r % 9;  int o = r / 9;
        s_w[t] = w[((size_t)(o * 128 + ci)) * 9 + tap];
    }
    __syncthreads();

    const int pos = blockIdx.x * 256 + threadIdx.x;   // 102400 exact
    const int pw = pos % 160, ph = (pos / 160) % 160, pn = pos / 25600;
    float acc[CO];
#pragma unroll
    for (int o = 0; o < CO; ++o) acc[o] = bias[o];

#pragma unroll
    for (int dh = 0; dh < 3; ++dh)
#pragma unroll
        for (int dw = 0; dw < 3; ++dw) {
            const int tap = dh * 3 + dw;
            const unsigned short* zp = z + ((size_t)((pn * 162 + ph + dh) * 162) + (pw + dw)) * 128;
            for (int c8 = 0; c8 < 16; ++c8) {
                uint4 v = *(const uint4*)(zp + c8 * 8);
                unsigned int ua[4] = {v.x, v.y, v.z, v.w};
                float xv[8];
#pragma unroll
                for (int j = 0; j < 4; ++j) {
                    xv[2 * j]     = bf2f((unsigned short)(ua[j] & 0xffffu));
                    xv[2 * j + 1] = bf2f((unsigned short)(ua[j] >> 16));
                }
#pragma unroll
                for (int o = 0; o < CO; ++o) {
                    const float* wp = &s_w[(o * 9 + tap) * 128 + c8 * 8];
                    float4 w0 = *(const float4*)wp;
                    float4 w1 = *(const float4*)(wp + 4);
                    acc[o] = fmaf(xv[0], w0.x, acc[o]);
                    acc[o] = fmaf(xv[1], w0.y, acc[o]);
                    acc[o] = fmaf(xv[2], w0.z, acc[o]);
                    acc[o] = fmaf(xv[3], w0.w, acc[o]);
                    acc[o] = fmaf(xv[4], w1.x, acc[o]);
                    acc[o] = fmaf(xv[5], w1.y, acc[o]);
                    acc[o] = fmaf(xv[6], w1.z, acc[o]);
                    acc[o] = fmaf(xv[7], w1.w, acc[o]);
                }
            }
        }
#pragma unroll
    for (int o = 0; o < CO; ++o)
        out[((size_t)(pn * CO + o)) * 25600 + ph * 160 + pw] = acc[o];
}

// two CO=1 heads fused (shrink + centroid)
__global__ __launch_bounds__(256) void head_conv_dual(const unsigned short* __restrict__ z,
                                                      const float* __restrict__ w1, const float* __restrict__ b1,
                                                      const float* __restrict__ w2, const float* __restrict__ b2,
                                                      float* __restrict__ out1, float* __restrict__ out2) {
    __shared__ float s_w[2 * 9 * 128];
    for (int t = threadIdx.x; t < 2 * 9 * 128; t += 256) {
        int ci = t % 128; int r = t / 128;
        int tap = r % 9;  int which = r / 9;
        const float* src = which ? w2 : w1;
        s_w[t] = src[(size_t)ci * 9 + tap];
    }
    __syncthreads();

    const int pos = blockIdx.x * 256 + threadIdx.x;
    const int pw = pos % 160, ph = (pos / 160) % 160, pn = pos / 25600;
    float a1 = b1[0], a2 = b2[0];

#pragma unroll
    for (int dh = 0; dh < 3; ++dh)
#pragma unroll
        for (int dw = 0; dw < 3; ++dw) {
            const int tap = dh * 3 + dw;
            const unsigned short* zp = z + ((size_t)((pn * 162 + ph + dh) * 162) + (pw + dw)) * 128;
            for (int c8 = 0; c8 < 16; ++c8) {
                uint4 v = *(const uint4*)(zp + c8 * 8);
                unsigned int ua[4] = {v.x, v.y, v.z, v.w};
                float xv[8];
#pragma unroll
                for (int j = 0; j < 4; ++j) {
                    xv[2 * j]     = bf2f((unsigned short)(ua[j] & 0xffffu));
                    xv[2 * j + 1] = bf2f((unsigned short)(ua[j] >> 16));
                }
                const float* wp1 = &s_w[tap * 128 + c8 * 8];
                const float* wp2 = &s_w[1152 + tap * 128 + c8 * 8];
#pragma unroll
                for (int e = 0; e < 8; ++e) {
                    a1 = fmaf(xv[e], wp1[e], a1);
                    a2 = fmaf(xv[e], wp2[e], a2);
                }
            }
        }
    out1[(size_t)pn * 25600 + ph * 160 + pw] = a1;
    out2[(size_t)pn * 25600 + ph * 160 + pw] = a2;
}

// ---------------------------------------------------------------------------
extern "C" void kernel_launch(void* const* d_in, const int* in_sizes, int n_in,
                              void* d_out, int out_size, void* d_ws, size_t ws_size,
                              hipStream_t stream) {
    const float* fpn = (const float*)d_in[0];
    const float* W1[3] = {(const float*)d_in[1],  (const float*)d_in[11], (const float*)d_in[19]};
    const float* G1[3] = {(const float*)d_in[2],  (const float*)d_in[12], (const float*)d_in[20]};
    const float* B1[3] = {(const float*)d_in[3],  (const float*)d_in[13], (const float*)d_in[21]};
    const float* W2[3] = {(const float*)d_in[4],  (const float*)d_in[14], (const float*)d_in[22]};
    const float* G2[3] = {(const float*)d_in[5],  (const float*)d_in[15], (const float*)d_in[23]};
    const float* B2[3] = {(const float*)d_in[6],  (const float*)d_in[16], (const float*)d_in[24]};
    const float* w_shrink = (const float*)d_in[7];  const float* b_shrink = (const float*)d_in[8];
    const float* w_cent   = (const float*)d_in[9];  const float* b_cent   = (const float*)d_in[10];
    const float* w_p3     = (const float*)d_in[17]; const float* b_p3     = (const float*)d_in[18];
    const float* w_s3     = (const float*)d_in[25]; const float* b_s3     = (const float*)d_in[26];
    float* out = (float*)d_out;

    const size_t S1 = (size_t)4 * 162 * 162 * 256;   // shorts per buf1
    const size_t S2 = (size_t)4 * 162 * 162 * 128;   // shorts per buf2
    const size_t need_fused = S1 * 2 * 4 /*xpad+3*buf1*/ + S2 * 2 * 3
                              + (size_t)9 * 294912 * 2 + 6 * 512 * 4;

    char* ws = (char*)d_ws;
    size_t off = 0;
    unsigned short* xpad = (unsigned short*)(ws + off); off += S1 * 2;
    const int NBR = (ws_size >= need_fused) ? 3 : 1;
    unsigned short* buf1 = (unsigned short*)(ws + off); off += S1 * 2 * NBR;
    unsigned short* buf2 = (unsigned short*)(ws + off); off += S2 * 2 * NBR;
    unsigned short* w1p  = (unsigned short*)(ws + off); off += (size_t)6 * 294912 * 2;
    unsigned short* w2p  = (unsigned short*)(ws + off); off += (size_t)3 * 294912 * 2;
    float* stats         = (float*)(ws + off);          off += (size_t)6 * 512 * 4;

    hipMemsetAsync(stats, 0, 6 * 512 * 4, stream);
    {
        int zthreads = 82432 * (1 + NBR) + 41216 * NBR;
        zero_all<<<(zthreads + 255) / 256, 256, 0, stream>>>(xpad, buf1, S1, buf2, S2, NBR);
    }
    transpose_pad<<<12800, 256, 0, stream>>>(fpn, xpad);
    pack_all<<<10368, 256, 0, stream>>>(W1[0], W1[1], W1[2], W2[0], W2[1], W2[2], w1p, w2p);

    if (NBR == 3) {
        // branch-fused: 3x blocks per dispatch, 4 big dispatches total
        conv3x3_mfma<256, 1600><<<4800, 256, 0, stream>>>(
            xpad, 0, w1p, (size_t)2 * 294912, buf1, S1, stats, 1024);
        bn_apply<256, 12800><<<38400, 256, 0, stream>>>(
            buf1, S1, stats, 1024, G1[0], G1[1], G1[2], B1[0], B1[1], B1[2]);
        conv3x3_mfma<128, 800><<<2400, 256, 0, stream>>>(
            buf1, S1, w2p, (size_t)294912, buf2, S2, stats + 512, 1024);
        bn_apply<128, 6400><<<19200, 256, 0, stream>>>(
            buf2, S2, stats + 512, 1024, G2[0], G2[1], G2[2], B2[0], B2[1], B2[2]);
        head_conv_dual<<<400, 256, 0, stream>>>(buf2, w_shrink, b_shrink, w_cent, b_cent,
                                                out, out + 102400);
        head_conv<2><<<400, 256, 0, stream>>>(buf2 + S2, w_p3, b_p3, out + 204800);
        head_conv<8><<<400, 256, 0, stream>>>(buf2 + 2 * S2, w_s3, b_s3, out + 409600);
    } else {
        // sequential fallback (R5 flow) if workspace is too small
        for (int br = 0; br < 3; ++br) {
            conv3x3_mfma<256, 1600><<<1600, 256, 0, stream>>>(
                xpad, 0, w1p + (size_t)br * 2 * 294912, 0, buf1, 0, stats + br * 1024, 0);
            bn_apply<256, 12800><<<12800, 256, 0, stream>>>(
                buf1, 0, stats + br * 1024, 0, G1[br], G1[br], G1[br], B1[br], B1[br], B1[br]);
            conv3x3_mfma<128, 800><<<800, 256, 0, stream>>>(
                buf1, 0, w2p + (size_t)br * 294912, 0, buf2, 0, stats + 512 + br * 1024, 0);
            bn_apply<128, 6400><<<6400, 256, 0, stream>>>(
                buf2, 0, stats + 512 + br * 1024, 0, G2[br], G2[br], G2[br], B2[br], B2[br], B2[br]);
            if (br == 0) {
                head_conv_dual<<<400, 256, 0, stream>>>(buf2, w_shrink, b_shrink, w_cent, b_cent,
                                                        out, out + 102400);
            } else if (br == 1) {
                head_conv<2><<<400, 256, 0, stream>>>(buf2, w_p3, b_p3, out + 204800);
            } else {
                head_conv<8><<<400, 256, 0, stream>>>(buf2, w_s3, b_s3, out + 409600);
            }
        }
    }
}

// Round 8
// 1517.465 us; speedup vs baseline: 1.5939x; 1.1724x over previous
//
#include <hip/hip_runtime.h>

typedef short bf16x8 __attribute__((ext_vector_type(8)));
typedef float f32x4 __attribute__((ext_vector_type(4)));

__device__ __forceinline__ float bf2f(unsigned short u) {
    union { unsigned int i; float f; } c; c.i = ((unsigned int)u) << 16; return c.f;
}
__device__ __forceinline__ unsigned short f2bf(float f) {
    union { float f; unsigned int i; } c; c.f = f;
    unsigned int u = c.i;
    u += 0x7fffu + ((u >> 16) & 1u);          // round-to-nearest-even
    return (unsigned short)(u >> 16);
}

// async global->LDS, 16B per lane; mapping must be wave-uniform base + lane*16
__device__ __forceinline__ void gload_lds16(const unsigned short* g, unsigned short* l) {
    __builtin_amdgcn_global_load_lds(
        (const __attribute__((address_space(1))) void*)g,
        (__attribute__((address_space(3))) void*)l, 16, 0, 0);
}

// ---------------------------------------------------------------------------
// fpn fp32 NCHW [4][256][160][160] -> bf16 NHWC padded [4][162][162][256]
__global__ void transpose_pad(const float* __restrict__ x, unsigned short* __restrict__ xpad) {
    int idx = blockIdx.x * 256 + threadIdx.x;       // 3,276,800 exact
    int w = idx % 160; int t = idx / 160;
    int cv = t % 32;   t /= 32;
    int h = t % 160;   int n = t / 160;
    const float* src = x + (((size_t)(n * 256 + cv * 8) * 160 + h) * 160 + w);
    unsigned short us[8];
#pragma unroll
    for (int k = 0; k < 8; ++k) us[k] = f2bf(src[(size_t)k * 25600]);
    uint4 o;
    o.x = (unsigned int)us[0] | ((unsigned int)us[1] << 16);
    o.y = (unsigned int)us[2] | ((unsigned int)us[3] << 16);
    o.z = (unsigned int)us[4] | ((unsigned int)us[5] << 16);
    o.w = (unsigned int)us[6] | ((unsigned int)us[7] << 16);
    *(uint4*)(xpad + ((size_t)((n * 162 + h + 1) * 162) + (w + 1)) * 256 + cv * 8) = o;
}

// zero the 1-wide border of one padded NHWC buffer
__device__ __forceinline__ void zero_border_one(unsigned short* buf, int C, int idx) {
    int CV = C >> 3;
    int cv = idx % CV; int t = idx / CV;
    int p = t % 644;   int n = t / 644;
    int h, w;
    if (p < 162)      { h = 0;   w = p; }
    else if (p < 324) { h = 161; w = p - 162; }
    else { int q = p - 324; h = 1 + (q >> 1); w = (q & 1) ? 161 : 0; }
    uint4 z = make_uint4(0u, 0u, 0u, 0u);
    *(uint4*)(buf + ((size_t)((n * 162 + h) * 162) + w) * C + cv * 8) = z;
}

// border-zero xpad + nbr buf1's (C=256) + nbr buf2's (C=128), one dispatch
__global__ void zero_all(unsigned short* __restrict__ xpad,
                         unsigned short* __restrict__ buf1, size_t s1,
                         unsigned short* __restrict__ buf2, size_t s2, int nbr) {
    int idx = blockIdx.x * 256 + threadIdx.x;
    if (idx < 82432) { zero_border_one(xpad, 256, idx); return; }
    idx -= 82432;
    int nb1 = nbr * 82432;
    if (idx < nb1) { zero_border_one(buf1 + (size_t)(idx / 82432) * s1, 256, idx % 82432); return; }
    idx -= nb1;
    int nb2 = nbr * 41216;
    if (idx < nb2) { zero_border_one(buf2 + (size_t)(idx / 41216) * s2, 128, idx % 41216); }
}

// ---------------------------------------------------------------------------
// Weight pack: fp32 OIHW [CO][256][3][3] -> per-128-co-tile fragment-order:
//   tile = 294912 shorts (576KB).
//   tp in 0..3 (taps {2tp,2tp+1}): block tp*65536; within: q(0..7)*8192;
//     idx = (g*128+co)*8+e, g 0..7: tap=2tp+(g>>2), ci=q*32+(g&3)*8+e
//   tp=4 (tap 8): block 262144, q*4096; idx=(g*128+co)*8+e, g 0..3: ci=q*32+g*8+e
// Tiles 0..5: layer1 (br=t>>1, coBase=(t&1)*128) -> w1p; 6..8: layer2 -> w2p.
__global__ void pack_all(const float* __restrict__ s0, const float* __restrict__ s1,
                         const float* __restrict__ s2, const float* __restrict__ s3,
                         const float* __restrict__ s4, const float* __restrict__ s5,
                         unsigned short* __restrict__ w1p, unsigned short* __restrict__ w2p) {
    int idx = blockIdx.x * 256 + threadIdx.x;   // 9*294912 = 2,654,208 exact
    int t = idx / 294912, r = idx - t * 294912;
    const float* src; unsigned short* dst; int coBase;
    if (t < 6) {
        int br = t >> 1;
        src = (br == 0) ? s0 : (br == 1) ? s1 : s2;
        coBase = (t & 1) * 128;
        dst = w1p + (size_t)t * 294912;
    } else {
        int br = t - 6;
        src = (br == 0) ? s3 : (br == 1) ? s4 : s5;
        coBase = 0;
        dst = w2p + (size_t)br * 294912;
    }
    int tap, ci, o;
    if (r < 262144) {
        int tp = r >> 16, rem = r & 65535;
        int q = rem >> 13, r2 = rem & 8191;
        int e = r2 & 7, gco = r2 >> 3;
        int co = gco & 127, g = gco >> 7;
        tap = tp * 2 + (g >> 2);
        ci = q * 32 + (g & 3) * 8 + e;
        o = coBase + co;
    } else {
        int rem = r - 262144;
        int q = rem >> 12, r2 = rem & 4095;
        int e = r2 & 7, gco = r2 >> 3;
        int co = gco & 127, g = gco >> 7;
        tap = 8;
        ci = q * 32 + g * 8 + e;
        o = coBase + co;
    }
    dst[r] = f2bf(src[((size_t)(o * 256 + ci)) * 9 + tap]);
}

// ---------------------------------------------------------------------------
// 3x3 conv, implicit GEMM, bf16 MFMA 16x16x32, strip-resident B at 32KB LDS.
// __launch_bounds__(256,3): cap total regs at 170 (arch<=106 + 64 acc) so
// 3 blocks/CU become resident (was 2 at VGPR 128+64=192). BPB = blocks per
// branch; branch-fused dispatch selects per-branch x/w/y/stats via strides.
template<int COT, int BPB>
__global__ __launch_bounds__(256, 3) void conv3x3_mfma(
        const unsigned short* __restrict__ xpad0, size_t xstride,
        const unsigned short* __restrict__ wpk0, size_t wstride,
        unsigned short* __restrict__ ypad0, size_t ystride,
        float* __restrict__ stats, int sstride) {
    __shared__ __align__(16) unsigned short Bs[4 * 256 * 8];   // [kg4][p256][8] 16KB
    __shared__ __align__(16) unsigned short As[8 * 128 * 8];   // [g8][co128][8] 16KB

    const int br = blockIdx.x / BPB;
    int bid = blockIdx.x % BPB;
    const unsigned short* xpad = xpad0 + (size_t)br * xstride;
    const unsigned short* wpk  = wpk0 + (size_t)br * wstride;
    unsigned short* ypad       = ypad0 + (size_t)br * ystride;
    float* sum   = stats + (size_t)br * sstride;
    float* sumsq = sum + 256;

    const int tid = threadIdx.x;
    const int wv = tid >> 6, lane = tid & 63;
    const int quad = lane >> 4, l15 = lane & 15;
    const int wr = wv >> 1, wc = wv & 1;

    const int wt = bid % 5;
    const int ht = (bid / 5) % 40;
    const int n = (bid / 200) % 4;
    const int tile = bid / 800;            // 0..1 for COT=256, 0 for COT=128
    const int co0 = tile * 128;
    const int h0 = ht * 4, w0 = wt * 32;   // halo origin in padded coords

    const unsigned short* wtile = wpk + (size_t)tile * 294912;
    // strip source: per-thread position (clamped), fixed across q
    int p = tid; if (p > 203) p = 203;
    const int ph = p / 34, pw = p - ph * 34;
    const unsigned short* bsrc0 = xpad +
        ((size_t)((n * 162 + h0 + ph) * 162) + (w0 + pw)) * 256;

    // b-frag base positions for this wave's 4 spatial frags
    int p0[4];
#pragma unroll
    for (int j = 0; j < 4; ++j) {
        int sp = wc * 64 + j * 16 + l15;
        p0[j] = (sp >> 5) * 34 + (sp & 31);
    }

    f32x4 acc[4][4];
#pragma unroll
    for (int i = 0; i < 4; ++i)
#pragma unroll
        for (int j = 0; j < 4; ++j) acc[i][j] = (f32x4){0.f, 0.f, 0.f, 0.f};

    for (int q = 0; q < 8; ++q) {          // ci chunk of 32
#pragma unroll
        for (int tp = 0; tp < 5; ++tp) {   // tap pairs {0,1}{2,3}{4,5}{6,7}{8}
            __syncthreads();               // prior window's LDS reads complete
            if (tp < 4) {
                const unsigned short* asrc = wtile + tp * 65536 + q * 8192 + tid * 8;
#pragma unroll
                for (int c = 0; c < 4; ++c)
                    gload_lds16(asrc + c * 2048, (unsigned short*)As + c * 2048 + tid * 8);
            } else {
                const unsigned short* asrc = wtile + 262144 + q * 4096 + tid * 8;
#pragma unroll
                for (int c = 0; c < 2; ++c)
                    gload_lds16(asrc + c * 2048, (unsigned short*)As + c * 2048 + tid * 8);
            }
            if (tp == 0) {
                const unsigned short* bsrc = bsrc0 + q * 32;
#pragma unroll
                for (int g = 0; g < 4; ++g)
                    gload_lds16(bsrc + g * 8, (unsigned short*)Bs + g * 2048 + tid * 8);
            }
            __syncthreads();               // drain DMA: tiles ready
#pragma unroll
            for (int ts = 0; ts < 2; ++ts) {
                if (tp == 4 && ts == 1) continue;   // folds at compile time
                const int tap = tp * 2 + ts;
                const int dh = tap / 3, dw = tap % 3;
                const int toff = dh * 34 + dw;
                const int g0 = (tp < 4 ? ts * 4 : 0) + quad;
                bf16x8 a[4], b[4];
#pragma unroll
                for (int i = 0; i < 4; ++i)
                    a[i] = *(const bf16x8*)(As + ((size_t)(g0 * 128 + wr * 64 + i * 16 + l15)) * 8);
#pragma unroll
                for (int j = 0; j < 4; ++j)
                    b[j] = *(const bf16x8*)(Bs + ((size_t)(quad * 256 + p0[j] + toff)) * 8);
#pragma unroll
                for (int i = 0; i < 4; ++i)
#pragma unroll
                    for (int j = 0; j < 4; ++j)
                        acc[i][j] = __builtin_amdgcn_mfma_f32_16x16x32_bf16(a[i], b[j], acc[i][j], 0, 0, 0);
            }
        }
    }

    // epilogue: store y (bf16, NHWC padded interior) + BN partial stats
#pragma unroll
    for (int i = 0; i < 4; ++i) {
        const int co_l = wr * 64 + i * 16 + quad * 4;
#pragma unroll
        for (int j = 0; j < 4; ++j) {
            const int sp = wc * 64 + j * 16 + l15;
            const int jh = sp >> 5, jw = sp & 31;
            f32x4 v = acc[i][j];
            ushort4 pk;
            pk.x = f2bf(v[0]); pk.y = f2bf(v[1]); pk.z = f2bf(v[2]); pk.w = f2bf(v[3]);
            *(ushort4*)(ypad + ((size_t)((n * 162 + h0 + jh + 1) * 162) + (w0 + jw + 1)) * COT
                        + co0 + co_l) = pk;
        }
#pragma unroll
        for (int r = 0; r < 4; ++r) {
            float s1 = 0.f, s2 = 0.f;
#pragma unroll
            for (int j = 0; j < 4; ++j) { float v = acc[i][j][r]; s1 += v; s2 += v * v; }
#pragma unroll
            for (int m = 1; m < 16; m <<= 1) {
                s1 += __shfl_xor(s1, m, 64);
                s2 += __shfl_xor(s2, m, 64);
            }
            if (l15 == 0) {
                atomicAdd(&sum[co0 + co_l + r], s1);
                atomicAdd(&sumsq[co0 + co_l + r], s2);
            }
        }
    }
}

// ---------------------------------------------------------------------------
// fused BN finalize + in-place relu(y*scale+shift); branch-fused via BPB
template<int C, int BPB>
__global__ void bn_apply(unsigned short* __restrict__ buf0, size_t bstride,
                         const float* __restrict__ stats, int sstride,
                         const float* g0, const float* g1, const float* g2,
                         const float* be0, const float* be1, const float* be2) {
    const int br = blockIdx.x / BPB;
    unsigned short* buf = buf0 + (size_t)br * bstride;
    const float* sum = stats + (size_t)br * sstride;
    const float* sumsq = sum + 256;
    const float* gamma = (br == 0) ? g0 : (br == 1) ? g1 : g2;
    const float* beta  = (br == 0) ? be0 : (br == 1) ? be1 : be2;

    __shared__ float s_sc[C], s_sh[C];
    if (threadIdx.x < C) {
        int c = threadIdx.x;
        const float inv = 1.0f / 102400.0f;
        float m = sum[c] * inv;
        float v = sumsq[c] * inv - m * m;
        float sc = gamma[c] * rsqrtf(v + 1e-5f);
        s_sc[c] = sc;
        s_sh[c] = beta[c] - m * sc;
    }
    __syncthreads();

    constexpr int CV = C / 8;
    int idx = (blockIdx.x % BPB) * 256 + threadIdx.x;   // 4*25600*CV exact per branch
    int cv = idx % CV; int pos = idx / CV;
    int w = pos % 160; int h = (pos / 160) % 160; int n = pos / 25600;
    unsigned short* p = buf + ((size_t)((n * 162 + h + 1) * 162) + (w + 1)) * C + cv * 8;
    uint4 v = *(const uint4*)p;
    unsigned int ua[4] = {v.x, v.y, v.z, v.w};
    unsigned int ob[4];
#pragma unroll
    for (int j = 0; j < 4; ++j) {
        int c = cv * 8 + j * 2;
        float f0 = bf2f((unsigned short)(ua[j] & 0xffffu)) * s_sc[c] + s_sh[c];
        float f1 = bf2f((unsigned short)(ua[j] >> 16)) * s_sc[c + 1] + s_sh[c + 1];
        f0 = fmaxf(f0, 0.f); f1 = fmaxf(f1, 0.f);
        ob[j] = (unsigned int)f2bf(f0) | ((unsigned int)f2bf(f1) << 16);
    }
    uint4 o = make_uint4(ob[0], ob[1], ob[2], ob[3]);
    *(uint4*)p = o;
}

// ---------------------------------------------------------------------------
// head conv: z [4][162][162][128] bf16 padded -> out [4][CO][160][160] fp32 (+bias)
template<int CO>
__global__ __launch_bounds__(256) void head_conv(const unsigned short* __restrict__ z,
                                                 const float* __restrict__ w,
                                                 const float* __restrict__ bias,
                                                 float* __restrict__ out) {
    __shared__ float s_w[CO * 9 * 128];
    for (int t = threadIdx.x; t < CO * 9 * 128; t += 256) {
        int ci = t % 128; int r = t / 128;
        int tap = r % 9;  int o = r / 9;
        s_w[t] = w[((size_t)(o * 128 + ci)) * 9 + tap];
    }
    __syncthreads();

    const int pos = blockIdx.x * 256 + threadIdx.x;   // 102400 exact
    const int pw = pos % 160, ph = (pos / 160) % 160, pn = pos / 25600;
    float acc[CO];
#pragma unroll
    for (int o = 0; o < CO; ++o) acc[o] = bias[o];

#pragma unroll
    for (int dh = 0; dh < 3; ++dh)
#pragma unroll
        for (int dw = 0; dw < 3; ++dw) {
            const int tap = dh * 3 + dw;
            const unsigned short* zp = z + ((size_t)((pn * 162 + ph + dh) * 162) + (pw + dw)) * 128;
            for (int c8 = 0; c8 < 16; ++c8) {
                uint4 v = *(const uint4*)(zp + c8 * 8);
                unsigned int ua[4] = {v.x, v.y, v.z, v.w};
                float xv[8];
#pragma unroll
                for (int j = 0; j < 4; ++j) {
                    xv[2 * j]     = bf2f((unsigned short)(ua[j] & 0xffffu));
                    xv[2 * j + 1] = bf2f((unsigned short)(ua[j] >> 16));
                }
#pragma unroll
                for (int o = 0; o < CO; ++o) {
                    const float* wp = &s_w[(o * 9 + tap) * 128 + c8 * 8];
                    float4 w0 = *(const float4*)wp;
                    float4 w1 = *(const float4*)(wp + 4);
                    acc[o] = fmaf(xv[0], w0.x, acc[o]);
                    acc[o] = fmaf(xv[1], w0.y, acc[o]);
                    acc[o] = fmaf(xv[2], w0.z, acc[o]);
                    acc[o] = fmaf(xv[3], w0.w, acc[o]);
                    acc[o] = fmaf(xv[4], w1.x, acc[o]);
                    acc[o] = fmaf(xv[5], w1.y, acc[o]);
                    acc[o] = fmaf(xv[6], w1.z, acc[o]);
                    acc[o] = fmaf(xv[7], w1.w, acc[o]);
                }
            }
        }
#pragma unroll
    for (int o = 0; o < CO; ++o)
        out[((size_t)(pn * CO + o)) * 25600 + ph * 160 + pw] = acc[o];
}

// two CO=1 heads fused (shrink + centroid)
__global__ __launch_bounds__(256) void head_conv_dual(const unsigned short* __restrict__ z,
                                                      const float* __restrict__ w1, const float* __restrict__ b1,
                                                      const float* __restrict__ w2, const float* __restrict__ b2,
                                                      float* __restrict__ out1, float* __restrict__ out2) {
    __shared__ float s_w[2 * 9 * 128];
    for (int t = threadIdx.x; t < 2 * 9 * 128; t += 256) {
        int ci = t % 128; int r = t / 128;
        int tap = r % 9;  int which = r / 9;
        const float* src = which ? w2 : w1;
        s_w[t] = src[(size_t)ci * 9 + tap];
    }
    __syncthreads();

    const int pos = blockIdx.x * 256 + threadIdx.x;
    const int pw = pos % 160, ph = (pos / 160) % 160, pn = pos / 25600;
    float a1 = b1[0], a2 = b2[0];

#pragma unroll
    for (int dh = 0; dh < 3; ++dh)
#pragma unroll
        for (int dw = 0; dw < 3; ++dw) {
            const int tap = dh * 3 + dw;
            const unsigned short* zp = z + ((size_t)((pn * 162 + ph + dh) * 162) + (pw + dw)) * 128;
            for (int c8 = 0; c8 < 16; ++c8) {
                uint4 v = *(const uint4*)(zp + c8 * 8);
                unsigned int ua[4] = {v.x, v.y, v.z, v.w};
                float xv[8];
#pragma unroll
                for (int j = 0; j < 4; ++j) {
                    xv[2 * j]     = bf2f((unsigned short)(ua[j] & 0xffffu));
                    xv[2 * j + 1] = bf2f((unsigned short)(ua[j] >> 16));
                }
                const float* wp1 = &s_w[tap * 128 + c8 * 8];
                const float* wp2 = &s_w[1152 + tap * 128 + c8 * 8];
#pragma unroll
                for (int e = 0; e < 8; ++e) {
                    a1 = fmaf(xv[e], wp1[e], a1);
                    a2 = fmaf(xv[e], wp2[e], a2);
                }
            }
        }
    out1[(size_t)pn * 25600 + ph * 160 + pw] = a1;
    out2[(size_t)pn * 25600 + ph * 160 + pw] = a2;
}

// ---------------------------------------------------------------------------
extern "C" void kernel_launch(void* const* d_in, const int* in_sizes, int n_in,
                              void* d_out, int out_size, void* d_ws, size_t ws_size,
                              hipStream_t stream) {
    const float* fpn = (const float*)d_in[0];
    const float* W1[3] = {(const float*)d_in[1],  (const float*)d_in[11], (const float*)d_in[19]};
    const float* G1[3] = {(const float*)d_in[2],  (const float*)d_in[12], (const float*)d_in[20]};
    const float* B1[3] = {(const float*)d_in[3],  (const float*)d_in[13], (const float*)d_in[21]};
    const float* W2[3] = {(const float*)d_in[4],  (const float*)d_in[14], (const float*)d_in[22]};
    const float* G2[3] = {(const float*)d_in[5],  (const float*)d_in[15], (const float*)d_in[23]};
    const float* B2[3] = {(const float*)d_in[6],  (const float*)d_in[16], (const float*)d_in[24]};
    const float* w_shrink = (const float*)d_in[7];  const float* b_shrink = (const float*)d_in[8];
    const float* w_cent   = (const float*)d_in[9];  const float* b_cent   = (const float*)d_in[10];
    const float* w_p3     = (const float*)d_in[17]; const float* b_p3     = (const float*)d_in[18];
    const float* w_s3     = (const float*)d_in[25]; const float* b_s3     = (const float*)d_in[26];
    float* out = (float*)d_out;

    const size_t S1 = (size_t)4 * 162 * 162 * 256;   // shorts per buf1
    const size_t S2 = (size_t)4 * 162 * 162 * 128;   // shorts per buf2
    const size_t need_fused = S1 * 2 * 4 /*xpad+3*buf1*/ + S2 * 2 * 3
                              + (size_t)9 * 294912 * 2 + 6 * 512 * 4;

    char* ws = (char*)d_ws;
    size_t off = 0;
    unsigned short* xpad = (unsigned short*)(ws + off); off += S1 * 2;
    const int NBR = (ws_size >= need_fused) ? 3 : 1;
    unsigned short* buf1 = (unsigned short*)(ws + off); off += S1 * 2 * NBR;
    unsigned short* buf2 = (unsigned short*)(ws + off); off += S2 * 2 * NBR;
    unsigned short* w1p  = (unsigned short*)(ws + off); off += (size_t)6 * 294912 * 2;
    unsigned short* w2p  = (unsigned short*)(ws + off); off += (size_t)3 * 294912 * 2;
    float* stats         = (float*)(ws + off);          off += (size_t)6 * 512 * 4;

    hipMemsetAsync(stats, 0, 6 * 512 * 4, stream);
    {
        int zthreads = 82432 * (1 + NBR) + 41216 * NBR;
        zero_all<<<(zthreads + 255) / 256, 256, 0, stream>>>(xpad, buf1, S1, buf2, S2, NBR);
    }
    transpose_pad<<<12800, 256, 0, stream>>>(fpn, xpad);
    pack_all<<<10368, 256, 0, stream>>>(W1[0], W1[1], W1[2], W2[0], W2[1], W2[2], w1p, w2p);

    if (NBR == 3) {
        // branch-fused: 3x blocks per dispatch, 4 big dispatches total
        conv3x3_mfma<256, 1600><<<4800, 256, 0, stream>>>(
            xpad, 0, w1p, (size_t)2 * 294912, buf1, S1, stats, 1024);
        bn_apply<256, 12800><<<38400, 256, 0, stream>>>(
            buf1, S1, stats, 1024, G1[0], G1[1], G1[2], B1[0], B1[1], B1[2]);
        conv3x3_mfma<128, 800><<<2400, 256, 0, stream>>>(
            buf1, S1, w2p, (size_t)294912, buf2, S2, stats + 512, 1024);
        bn_apply<128, 6400><<<19200, 256, 0, stream>>>(
            buf2, S2, stats + 512, 1024, G2[0], G2[1], G2[2], B2[0], B2[1], B2[2]);
        head_conv_dual<<<400, 256, 0, stream>>>(buf2, w_shrink, b_shrink, w_cent, b_cent,
                                                out, out + 102400);
        head_conv<2><<<400, 256, 0, stream>>>(buf2 + S2, w_p3, b_p3, out + 204800);
        head_conv<8><<<400, 256, 0, stream>>>(buf2 + 2 * S2, w_s3, b_s3, out + 409600);
    } else {
        // sequential fallback (R5 flow) if workspace is too small
        for (int br = 0; br < 3; ++br) {
            conv3x3_mfma<256, 1600><<<1600, 256, 0, stream>>>(
                xpad, 0, w1p + (size_t)br * 2 * 294912, 0, buf1, 0, stats + br * 1024, 0);
            bn_apply<256, 12800><<<12800, 256, 0, stream>>>(
                buf1, 0, stats + br * 1024, 0, G1[br], G1[br], G1[br], B1[br], B1[br], B1[br]);
            conv3x3_mfma<128, 800><<<800, 256, 0, stream>>>(
                buf1, 0, w2p + (size_t)br * 294912, 0, buf2, 0, stats + 512 + br * 1024, 0);
            bn_apply<128, 6400><<<6400, 256, 0, stream>>>(
                buf2, 0, stats + 512 + br * 1024, 0, G2[br], G2[br], G2[br], B2[br], B2[br], B2[br]);
            if (br == 0) {
                head_conv_dual<<<400, 256, 0, stream>>>(buf2, w_shrink, b_shrink, w_cent, b_cent,
                                                        out, out + 102400);
            } else if (br == 1) {
                head_conv<2><<<400, 256, 0, stream>>>(buf2, w_p3, b_p3, out + 204800);
            } else {
                head_conv<8><<<400, 256, 0, stream>>>(buf2, w_s3, b_s3, out + 409600);
            }
        }
    }
}